// Round 7
// baseline (880.474 us; speedup 1.0000x reference)
//
#include <hip/hip_runtime.h>
#include <hip/hip_fp16.h>

#define NN 100000
#define NE 3200000
#define NB 1563            // ceil(NN/64) buckets of 64 receiver nodes
#define NG 8               // XCD groups (real HW_REG_XCC_ID)
#define NB8 (NB * NG)      // 12504 sub-buckets
#define NBLK ((NN + 255) / 256)
#define PREP_GRID 1024     // must be <= co-resident capacity (launch_bounds 256,4 -> 4/CU*256CU)
#define CAP 4096           // max edges per 64-node bucket (mean 2048, sigma ~45)

typedef float f32x4 __attribute__((ext_vector_type(4)));
typedef unsigned int u32x4 __attribute__((ext_vector_type(4)));

__device__ __forceinline__ float2 h2f2(unsigned int u) {
  __half2 h;
  *reinterpret_cast<unsigned int*>(&h) = u;
  return __half22float2(h);
}
__device__ __forceinline__ unsigned int f2h2(float x, float y) {
  __half2 h = __floats2half2_rn(x, y);
  return *reinterpret_cast<unsigned int*>(&h);
}

// ---------------- fused count + scan + scatter, XCD-pinned sub-buckets ----------------
// g = real XCD id (s_getreg HW_REG_XCC_ID). A block counts AND scatters with the same g
// (it never migrates), so per-(bucket,XCD) counts match claims exactly. Sub-bucket tail
// lines are written by exactly one XCD -> stay in that XCD's L2 until full -> ~1x write amp.

__global__ __launch_bounds__(256, 4) void k_prep(const int* __restrict__ send, const int* __restrict__ recv,
                                                 const float* __restrict__ ef, const float* __restrict__ mask,
                                                 int* __restrict__ cnt, int* __restrict__ boff,
                                                 int* __restrict__ cursor, float4* __restrict__ sorted,
                                                 int* __restrict__ bar) {
  unsigned xcc;
  asm volatile("s_getreg_b32 %0, hwreg(HW_REG_XCC_ID)" : "=s"(xcc));
  int g = xcc & 7;
  int tid = blockIdx.x * 256 + threadIdx.x;
  const int stride = PREP_GRID * 256;

  // phase 1: per-(bucket, my-XCD) histogram. cnt layout g-major: cnt[g*NB + b]
  int* cntg = cnt + g * NB;
  for (int i = tid; i < NE; i += stride) {
    int r = __builtin_nontemporal_load(recv + i);
    atomicAdd(&cntg[r >> 6], 1);
  }

  // grid barrier 1 (all 1024 blocks co-resident by launch_bounds)
  __syncthreads();
  if (threadIdx.x == 0) {
    __threadfence();
    atomicAdd(&bar[0], 1);
    while (atomicAdd(&bar[0], 0) < PREP_GRID) __builtin_amdgcn_s_sleep(8);
  }
  __syncthreads();

  // phase 2: block 0 scans all 12504 sub-buckets in (b major, g minor) order.
  // Cross-XCD values -> agent-scope atomic loads/stores (per-XCD L2s not coherent).
  if (blockIdx.x == 0) {
    __shared__ int ps[256];
    int t = threadIdx.x;
    const int PER = (NB8 + 255) / 256;  // 49
    int s = 0;
    for (int k = 0; k < PER; k++) {
      int idx = t * PER + k;
      if (idx < NB8)
        s += __hip_atomic_load(&cnt[(idx & 7) * NB + (idx >> 3)], __ATOMIC_RELAXED, __HIP_MEMORY_SCOPE_AGENT);
    }
    ps[t] = s;
    __syncthreads();
    for (int o = 1; o < 256; o <<= 1) {
      int x = (t >= o) ? ps[t - o] : 0;
      __syncthreads();
      ps[t] += x;
      __syncthreads();
    }
    int run = (t > 0) ? ps[t - 1] : 0;
    for (int k = 0; k < PER; k++) {
      int idx = t * PER + k;
      if (idx < NB8) {
        int b = idx >> 3, gg = idx & 7;
        int c = __hip_atomic_load(&cnt[gg * NB + b], __ATOMIC_RELAXED, __HIP_MEMORY_SCOPE_AGENT);
        boff[idx] = run;  // bucket-major offsets for k_bsort (read by later kernel)
        __hip_atomic_store(&cursor[gg * NB + b], run, __ATOMIC_RELAXED, __HIP_MEMORY_SCOPE_AGENT);
        run += c;
      }
    }
    if (t == 255) boff[NB8] = run;
    __threadfence();
  }

  // grid barrier 2
  __syncthreads();
  if (threadIdx.x == 0) {
    atomicAdd(&bar[1], 1);
    while (atomicAdd(&bar[1], 0) < PREP_GRID) __builtin_amdgcn_s_sleep(8);
  }
  __syncthreads();

  // phase 3: scatter with the SAME g -> claims exactly match phase-1 counts
  int* curg = cursor + g * NB;
  for (int i = tid; i < NE; i += stride) {
    int r = __builtin_nontemporal_load(recv + i);
    int s = __builtin_nontemporal_load(send + i);
    float e0 = __builtin_nontemporal_load(ef + 2 * i);
    float e1 = __builtin_nontemporal_load(ef + 2 * i + 1);
    float mk = __builtin_nontemporal_load(mask + i);
    int pos = atomicAdd(&curg[r >> 6], 1);
    float4 v;
    v.x = __int_as_float((s << 6) | (r & 63));  // 17b sender | 6b local receiver
    v.y = e0;
    v.z = e1;
    v.w = mk;
    sorted[pos] = v;
  }
}

// ---------------- per-bucket counting sort by key=(rl, sender>>11) + row_off ----------------
// Major digit rl  -> contiguous per-node CSR segments (register accumulation, no atomics).
// Minor digit s>>11 -> each node's edges walk sender space; all nodes in lockstep =>
// chip-wide gather window stays small and L2-resident.

__global__ __launch_bounds__(256) void k_bsort(const int* __restrict__ boff, float4* __restrict__ sorted,
                                               int* __restrict__ row_off) {
  __shared__ int cnt[4096];
  __shared__ int part[256];
  __shared__ float4 stg[CAP];
  int t = threadIdx.x, b = blockIdx.x;
  int base = boff[b * NG], end = boff[(b + 1) * NG];
  int Eb = end - base;
  int n0 = b * 64;
  for (int i = t; i < 4096; i += 256) cnt[i] = 0;
  __syncthreads();
  for (int e = base + t; e < end; e += 256) {
    int pk = __float_as_int(sorted[e].x);
    int key = ((pk & 63) << 6) | (pk >> 17);  // rl major, sender-granule minor
    atomicAdd(&cnt[key], 1);
  }
  __syncthreads();
  int s = 0;
#pragma unroll
  for (int k = 0; k < 16; k++) s += cnt[t * 16 + k];
  part[t] = s;
  __syncthreads();
  for (int o = 1; o < 256; o <<= 1) {
    int x = (t >= o) ? part[t - o] : 0;
    __syncthreads();
    part[t] += x;
    __syncthreads();
  }
  int run = part[t] - s;  // exclusive prefix of this thread's 16 bins
#pragma unroll
  for (int k = 0; k < 16; k++) {
    int c = cnt[t * 16 + k];
    cnt[t * 16 + k] = run;
    run += c;
  }
  __syncthreads();
  if (t < 64) {
    int n = n0 + t;
    if (n < NN) row_off[n] = base + cnt[t << 6];  // start of rl's first bin
  }
  if (b == NB - 1 && t == 0) row_off[NN] = end;
  __syncthreads();
  for (int e = base + t; e < end; e += 256) {
    float4 r = sorted[e];
    int pk = __float_as_int(r.x);
    int key = ((pk & 63) << 6) | (pk >> 17);
    int p = atomicAdd(&cnt[key], 1);
    stg[p] = r;
  }
  __syncthreads();
  for (int i = t; i < Eb; i += 256) sorted[base + i] = stg[i];
}

// ---------------- init: h = PQ@W_in + b_in ; Vp=(1,0); layer-0 a,b projections ----------------
// a stored fp16 node-major: a[n*32 + ch] -> one 64B line per node.

__global__ __launch_bounds__(256) void k_init(const float2* __restrict__ PQ,
                                              const float* __restrict__ Win, const float* __restrict__ bin,
                                              const float* __restrict__ Wm, const float* __restrict__ bm,
                                              float* __restrict__ h, __half* __restrict__ a,
                                              float* __restrict__ bp, float2* __restrict__ Vp) {
  int n = blockIdx.x * 256 + threadIdx.x;
  if (n >= NN) return;
  float2 pq = PQ[n];
  float hh[32];
#pragma unroll
  for (int j = 0; j < 32; j++) hh[j] = fmaf(pq.x, Win[j], fmaf(pq.y, Win[32 + j], bin[j]));
  float4* h4 = (float4*)(h + (size_t)n * 32);
#pragma unroll
  for (int j = 0; j < 8; j++) h4[j] = make_float4(hh[4*j], hh[4*j+1], hh[4*j+2], hh[4*j+3]);
  Vp[n] = make_float2(1.0f, 0.0f);
  float av[32], bv[32];
#pragma unroll
  for (int j = 0; j < 32; j++) { av[j] = Wm[j]; bv[j] = Wm[34 * 32 + j] + bm[j]; }
#pragma unroll 1
  for (int k = 0; k < 32; k++) {
    float hk = hh[k];
#pragma unroll
    for (int j = 0; j < 32; j++) {
      av[j] = fmaf(hk, Wm[(2 + k) * 32 + j], av[j]);
      bv[j] = fmaf(hk, Wm[(36 + k) * 32 + j], bv[j]);
    }
  }
  u32x4* dst = (u32x4*)(a + (size_t)n * 32);
#pragma unroll
  for (int g = 0; g < 4; g++) {
    u32x4 p;
    p.x = f2h2(av[g*8+0], av[g*8+1]);
    p.y = f2h2(av[g*8+2], av[g*8+3]);
    p.z = f2h2(av[g*8+4], av[g*8+5]);
    p.w = f2h2(av[g*8+6], av[g*8+7]);
    dst[g] = p;
  }
  float4* b4 = (float4*)(bp + (size_t)n * 32);
#pragma unroll
  for (int j = 0; j < 8; j++) b4[j] = make_float4(bv[4*j], bv[4*j+1], bv[4*j+2], bv[4*j+3]);
}

// ---------------- per-layer edge aggregation: CSR quad-gather, register accum, NO atomics ----------------
// 4 lanes per node (8 ch each); node's edges sender-granule-sorted; record load is quad-broadcast.

__global__ __launch_bounds__(256) void k_edge(const __half* __restrict__ a, const float* __restrict__ bp,
                                              const int* __restrict__ row_off, const f32x4* __restrict__ sorted,
                                              const float* __restrict__ Wm, float* __restrict__ agg) {
  int t = threadIdx.x;
  int n = blockIdx.x * 64 + (t >> 2);
  if (n >= NN) return;
  int ch = (t & 3) * 8;
  const float* wr = Wm + 68 * 32 + ch;
  float w0[8], w1[8];
#pragma unroll
  for (int j = 0; j < 8; j++) { w0[j] = wr[j]; w1[j] = wr[32 + j]; }
  const float4 bna = *(const float4*)(bp + (size_t)n * 32 + ch);
  const float4 bnb = *(const float4*)(bp + (size_t)n * 32 + ch + 4);
  float bn[8] = {bna.x, bna.y, bna.z, bna.w, bnb.x, bnb.y, bnb.z, bnb.w};
  float acc[8] = {0.f, 0.f, 0.f, 0.f, 0.f, 0.f, 0.f, 0.f};
  int e0 = row_off[n], e1 = row_off[n + 1];
  f32x4 rec = {0.f, 0.f, 0.f, 0.f};
  if (e0 < e1) rec = __builtin_nontemporal_load(sorted + e0);
#pragma unroll 2
  for (int e = e0; e < e1; ++e) {
    int pk = __float_as_int(rec.x);
    float c0 = rec.y, c1 = rec.z, mk = rec.w;
    const u32x4 pa = *(const u32x4*)(a + (size_t)(pk >> 6) * 32 + ch);  // 16B of sender's 64B line
    if (e + 1 < e1) rec = __builtin_nontemporal_load(sorted + e + 1);   // prefetch next record
    float2 f0 = h2f2(pa.x), f1 = h2f2(pa.y), f2 = h2f2(pa.z), f3 = h2f2(pa.w);
    float av[8] = {f0.x, f0.y, f1.x, f1.y, f2.x, f2.y, f3.x, f3.y};
#pragma unroll
    for (int j = 0; j < 8; j++)
      acc[j] = fmaf(fmaxf(av[j] + fmaf(c0, w0[j], fmaf(c1, w1[j], bn[j])), 0.f), mk, acc[j]);
  }
  float* gp = agg + (size_t)n * 32 + ch;
  *(float4*)gp       = make_float4(acc[0], acc[1], acc[2], acc[3]);
  *(float4*)(gp + 4) = make_float4(acc[4], acc[5], acc[6], acc[7]);
}

// ---------------- per-layer node update (+ next-layer projections fused) ----------------

__global__ __launch_bounds__(256) void k_node(const float* __restrict__ agg,
                                              const float* __restrict__ Wu, const float* __restrict__ bu,
                                              const float* __restrict__ Wd, const float* __restrict__ bd,
                                              const float* __restrict__ Wm, const float* __restrict__ bm,
                                              float* __restrict__ h, __half* __restrict__ a,
                                              float* __restrict__ bp, float2* __restrict__ Vp,
                                              float2* __restrict__ out, int last) {
  int n = blockIdx.x * 256 + threadIdx.x;
  if (n >= NN) return;
  float2 vp = Vp[n];
  float v0 = vp.x, v1 = vp.y;
  float hh[32], ag[32];
  const float4* h4 = (const float4*)(h + (size_t)n * 32);
  const float4* g4 = (const float4*)(agg + (size_t)n * 32);
#pragma unroll
  for (int jj = 0; jj < 8; jj++) {
    float4 x = h4[jj];
    hh[4*jj] = x.x; hh[4*jj+1] = x.y; hh[4*jj+2] = x.z; hh[4*jj+3] = x.w;
    float4 y = g4[jj];
    ag[4*jj] = y.x; ag[4*jj+1] = y.y; ag[4*jj+2] = y.z; ag[4*jj+3] = y.w;
  }
  float vo[32];
#pragma unroll
  for (int j = 0; j < 32; j++) vo[j] = fmaf(v0, Wu[j], fmaf(v1, Wu[32 + j], bu[j]));
#pragma unroll 1
  for (int k = 0; k < 32; k++) {
    float hk = hh[k], ak = ag[k];
#pragma unroll
    for (int j = 0; j < 32; j++) {
      vo[j] = fmaf(hk, Wu[(2 + k) * 32 + j], vo[j]);
      vo[j] = fmaf(ak, Wu[(34 + k) * 32 + j], vo[j]);
    }
  }
#pragma unroll
  for (int j = 0; j < 32; j++) hh[j] = fmaxf(vo[j], 0.0f);
  float d0 = bd[0], d1 = bd[1];
#pragma unroll 1
  for (int k = 0; k < 32; k++) {
    d0 = fmaf(hh[k], Wd[2 * k], d0);
    d1 = fmaf(hh[k], Wd[2 * k + 1], d1);
  }
  v0 += d0;
  v1 += d1;
  if (last) {
    out[n] = make_float2(v0, v1);
    return;
  }
  Vp[n] = make_float2(v0, v1);
  float4* hw4 = (float4*)(h + (size_t)n * 32);
#pragma unroll
  for (int jj = 0; jj < 8; jj++) hw4[jj] = make_float4(hh[4*jj], hh[4*jj+1], hh[4*jj+2], hh[4*jj+3]);
  float av[32], bv[32];
#pragma unroll
  for (int j = 0; j < 32; j++) {
    av[j] = fmaf(v0, Wm[j], v1 * Wm[32 + j]);
    bv[j] = fmaf(v0, Wm[34 * 32 + j], fmaf(v1, Wm[35 * 32 + j], bm[j]));
  }
#pragma unroll 1
  for (int k = 0; k < 32; k++) {
    float hk = hh[k];
#pragma unroll
    for (int j = 0; j < 32; j++) {
      av[j] = fmaf(hk, Wm[(2 + k) * 32 + j], av[j]);
      bv[j] = fmaf(hk, Wm[(36 + k) * 32 + j], bv[j]);
    }
  }
  u32x4* dst = (u32x4*)(a + (size_t)n * 32);
#pragma unroll
  for (int g = 0; g < 4; g++) {
    u32x4 p;
    p.x = f2h2(av[g*8+0], av[g*8+1]);
    p.y = f2h2(av[g*8+2], av[g*8+3]);
    p.z = f2h2(av[g*8+4], av[g*8+5]);
    p.w = f2h2(av[g*8+6], av[g*8+7]);
    dst[g] = p;
  }
  float4* b4 = (float4*)(bp + (size_t)n * 32);
#pragma unroll
  for (int jj = 0; jj < 8; jj++) b4[jj] = make_float4(bv[4*jj], bv[4*jj+1], bv[4*jj+2], bv[4*jj+3]);
}

// ---------------- launch ----------------

extern "C" void kernel_launch(void* const* d_in, const int* in_sizes, int n_in,
                              void* d_out, int out_size, void* d_ws, size_t ws_size,
                              hipStream_t stream) {
  const float* PQ   = (const float*)d_in[0];
  const int*   send = (const int*)d_in[1];
  const int*   recv = (const int*)d_in[2];
  const float* ef   = (const float*)d_in[3];
  const float* mask = (const float*)d_in[4];
  const float* Win  = (const float*)d_in[5];
  const float* bin  = (const float*)d_in[6];
  const float* Wmsg = (const float*)d_in[7];   // [3,70,32]
  const float* bmsg = (const float*)d_in[8];   // [3,32]
  const float* Wupd = (const float*)d_in[9];   // [3,66,32]
  const float* bupd = (const float*)d_in[10];  // [3,32]
  const float* Wdel = (const float*)d_in[11];  // [3,32,2]
  const float* bdel = (const float*)d_in[12];  // [3,2]
  float2* out = (float2*)d_out;

  char* w = (char*)d_ws;
  auto alloc = [&](size_t bytes) {
    char* p = w;
    w += (bytes + 255) & ~(size_t)255;
    return p;
  };
  float4* sorted = (float4*)alloc((size_t)NE * 16);
  int* cnt     = (int*)alloc((size_t)NB8 * 4);
  int* boff    = (int*)alloc(((size_t)NB8 + 1) * 4);
  int* cursor  = (int*)alloc((size_t)NB8 * 4);
  int* row_off = (int*)alloc(((size_t)NN + 1) * 4);
  int* bar     = (int*)alloc(256);
  float* h    = (float*)alloc((size_t)NN * 32 * 4);
  __half* a   = (__half*)alloc((size_t)NN * 32 * 2);
  float* bp   = (float*)alloc((size_t)NN * 32 * 4);
  float* agg  = (float*)alloc((size_t)NN * 32 * 4);
  float2* Vp  = (float2*)alloc((size_t)NN * 8);

  hipMemsetAsync(cnt, 0, (size_t)NB8 * 4, stream);
  hipMemsetAsync(bar, 0, 256, stream);
  k_prep<<<PREP_GRID, 256, 0, stream>>>(send, recv, ef, mask, cnt, boff, cursor, sorted, bar);
  k_bsort<<<NB, 256, 0, stream>>>(boff, sorted, row_off);

  k_init<<<NBLK, 256, 0, stream>>>((const float2*)PQ, Win, bin, Wmsg, bmsg, h, a, bp, Vp);

  for (int l = 0; l < 3; l++) {
    int last = (l == 2) ? 1 : 0;
    int lnext = (l + 1) % 3;
    k_edge<<<NB, 256, 0, stream>>>(a, bp, row_off, (const f32x4*)sorted, Wmsg + l * 70 * 32, agg);
    k_node<<<NBLK, 256, 0, stream>>>(agg, Wupd + l * 66 * 32, bupd + l * 32,
                                     Wdel + l * 64, bdel + l * 2,
                                     Wmsg + lnext * 70 * 32, bmsg + lnext * 32,
                                     h, a, bp, Vp, out, last);
  }
}

// Round 8
// 602.966 us; speedup vs baseline: 1.4602x; 1.4602x over previous
//
#include <hip/hip_runtime.h>
#include <hip/hip_fp16.h>

#define NN 100000
#define NE 3200000
#define NB 1563            // ceil(NN/64) buckets of 64 receiver nodes
#define NBLK ((NN + 255) / 256)
#define CHUNK 8192
#define NCH 391            // ceil(NE/CHUNK)
#define CAP 4096           // max edges per 64-node bucket (mean 2048, sigma ~45)

typedef float f32x4 __attribute__((ext_vector_type(4)));
typedef unsigned int u32x4 __attribute__((ext_vector_type(4)));

__device__ __forceinline__ float2 h2f2(unsigned int u) {
  __half2 h;
  *reinterpret_cast<unsigned int*>(&h) = u;
  return __half22float2(h);
}
__device__ __forceinline__ unsigned int f2h2(float x, float y) {
  __half2 h = __floats2half2_rn(x, y);
  return *reinterpret_cast<unsigned int*>(&h);
}

// ---------------- pass 1: per-chunk bucket histogram ----------------
// histmat[b*NCH + c] = #edges of bucket b in chunk c

__global__ __launch_bounds__(256) void k_hist(const int* __restrict__ recv, int* __restrict__ histmat) {
  __shared__ int h[NB];
  int t = threadIdx.x, c = blockIdx.x;
  for (int i = t; i < NB; i += 256) h[i] = 0;
  __syncthreads();
  int start = c * CHUNK;
  int end = min(start + CHUNK, NE);
  for (int i = start + t; i < end; i += 256)
    atomicAdd(&h[__builtin_nontemporal_load(recv + i) >> 6], 1);
  __syncthreads();
  for (int i = t; i < NB; i += 256) histmat[i * NCH + c] = h[i];
}

// ---------------- scan A: per-bucket totals ----------------

__global__ __launch_bounds__(64) void k_scanA(const int* __restrict__ histmat, int* __restrict__ total) {
  __shared__ int ps[64];
  int t = threadIdx.x, b = blockIdx.x;
  int s = 0;
  for (int c = t; c < NCH; c += 64) s += histmat[b * NCH + c];
  ps[t] = s;
  __syncthreads();
  for (int o = 32; o > 0; o >>= 1) {
    if (t < o) ps[t] += ps[t + o];
    __syncthreads();
  }
  if (t == 0) total[b] = ps[0];
}

// ---------------- scan B: exclusive scan of bucket totals -> boff[b] ----------------

__global__ __launch_bounds__(256) void k_scanB(const int* __restrict__ total, int* __restrict__ boff) {
  __shared__ int ps[256];
  int t = threadIdx.x;
  const int PER = (NB + 255) / 256;  // 7
  int v[PER];
  int s = 0;
#pragma unroll
  for (int k = 0; k < PER; k++) {
    int i = t * PER + k;
    v[k] = (i < NB) ? total[i] : 0;
    s += v[k];
  }
  ps[t] = s;
  __syncthreads();
  for (int o = 1; o < 256; o <<= 1) {
    int x = (t >= o) ? ps[t - o] : 0;
    __syncthreads();
    ps[t] += x;
    __syncthreads();
  }
  int run = (t > 0) ? ps[t - 1] : 0;
#pragma unroll
  for (int k = 0; k < PER; k++) {
    int i = t * PER + k;
    if (i < NB) {
      boff[i] = run;
      run += v[k];
    }
  }
  if (t == 255) boff[NB] = ps[255];
}

// ---------------- scan C: in-place exclusive scan of chunk counts within bucket ----------------
// histmat[b*NCH + c] becomes the absolute destination offset of chunk c's segment of bucket b.

__global__ __launch_bounds__(64) void k_scanC(int* __restrict__ histmat, const int* __restrict__ boff) {
  __shared__ int ps[64];
  int t = threadIdx.x, b = blockIdx.x;
  const int PER = (NCH + 63) / 64;  // 7
  int v[PER];
  int s = 0;
#pragma unroll
  for (int k = 0; k < PER; k++) {
    int c = t * PER + k;
    v[k] = (c < NCH) ? histmat[b * NCH + c] : 0;
    s += v[k];
  }
  ps[t] = s;
  __syncthreads();
  for (int o = 1; o < 64; o <<= 1) {
    int x = (t >= o) ? ps[t - o] : 0;
    __syncthreads();
    ps[t] += x;
    __syncthreads();
  }
  int run = boff[b] + ((t > 0) ? ps[t - 1] : 0);
#pragma unroll
  for (int k = 0; k < PER; k++) {
    int c = t * PER + k;
    if (c < NCH) {
      histmat[b * NCH + c] = run;
      run += v[k];
    }
  }
}

// ---------------- pass 2: scatter, block-owned contiguous segments, no global atomics ----------------

__global__ __launch_bounds__(256) void k_scat(const int* __restrict__ send, const int* __restrict__ recv,
                                              const float2* __restrict__ ef, const float* __restrict__ mask,
                                              const int* __restrict__ boffc, float4* __restrict__ sorted) {
  __shared__ int lcnt[NB];
  int t = threadIdx.x, c = blockIdx.x;
  for (int i = t; i < NB; i += 256) lcnt[i] = 0;
  __syncthreads();
  int start = c * CHUNK;
  int end = min(start + CHUNK, NE);
  for (int i = start + t; i < end; i += 256) {
    int r = __builtin_nontemporal_load(recv + i);
    int s = __builtin_nontemporal_load(send + i);
    float2 e2 = ef[i];
    float mk = __builtin_nontemporal_load(mask + i);
    int b = r >> 6;
    int rank = atomicAdd(&lcnt[b], 1);
    int dst = boffc[b * NCH + c] + rank;
    float4 v;
    v.x = __int_as_float((s << 6) | (r & 63));  // 17b sender | 6b local receiver
    v.y = e2.x;
    v.z = e2.y;
    v.w = mk;
    sorted[dst] = v;
  }
}

// ---------------- per-bucket counting sort by key=(rl, sender>>11) + row_off ----------------
// Major digit rl  -> contiguous per-node CSR segments (register accumulation, no atomics).
// Minor digit s>>11 -> each node's edges walk sender space; all nodes in lockstep =>
// chip-wide gather window stays small and L2-resident.

__global__ __launch_bounds__(256) void k_bsort(const int* __restrict__ boff, float4* __restrict__ sorted,
                                               int* __restrict__ row_off) {
  __shared__ int cnt[4096];
  __shared__ int part[256];
  __shared__ float4 stg[CAP];
  int t = threadIdx.x, b = blockIdx.x;
  int base = boff[b], end = boff[b + 1];
  int Eb = end - base;
  int n0 = b * 64;
  for (int i = t; i < 4096; i += 256) cnt[i] = 0;
  __syncthreads();
  for (int e = base + t; e < end; e += 256) {
    int pk = __float_as_int(sorted[e].x);
    int key = ((pk & 63) << 6) | (pk >> 17);  // rl major, sender-granule minor
    atomicAdd(&cnt[key], 1);
  }
  __syncthreads();
  int s = 0;
#pragma unroll
  for (int k = 0; k < 16; k++) s += cnt[t * 16 + k];
  part[t] = s;
  __syncthreads();
  for (int o = 1; o < 256; o <<= 1) {
    int x = (t >= o) ? part[t - o] : 0;
    __syncthreads();
    part[t] += x;
    __syncthreads();
  }
  int run = part[t] - s;  // exclusive prefix of this thread's 16 bins
#pragma unroll
  for (int k = 0; k < 16; k++) {
    int c = cnt[t * 16 + k];
    cnt[t * 16 + k] = run;
    run += c;
  }
  __syncthreads();
  if (t < 64) {
    int n = n0 + t;
    if (n < NN) row_off[n] = base + cnt[t << 6];  // start of rl's first bin
  }
  if (b == NB - 1 && t == 0) row_off[NN] = end;
  __syncthreads();
  for (int e = base + t; e < end; e += 256) {
    float4 r = sorted[e];
    int pk = __float_as_int(r.x);
    int key = ((pk & 63) << 6) | (pk >> 17);
    int p = atomicAdd(&cnt[key], 1);
    stg[p] = r;
  }
  __syncthreads();
  for (int i = t; i < Eb; i += 256) sorted[base + i] = stg[i];
}

// ---------------- init: h = PQ@W_in + b_in ; Vp=(1,0); layer-0 a,b projections ----------------
// a stored fp16 node-major: a[n*32 + ch] -> one 64B line per node.

__global__ __launch_bounds__(256) void k_init(const float2* __restrict__ PQ,
                                              const float* __restrict__ Win, const float* __restrict__ bin,
                                              const float* __restrict__ Wm, const float* __restrict__ bm,
                                              float* __restrict__ h, __half* __restrict__ a,
                                              float* __restrict__ bp, float2* __restrict__ Vp) {
  int n = blockIdx.x * 256 + threadIdx.x;
  if (n >= NN) return;
  float2 pq = PQ[n];
  float hh[32];
#pragma unroll
  for (int j = 0; j < 32; j++) hh[j] = fmaf(pq.x, Win[j], fmaf(pq.y, Win[32 + j], bin[j]));
  float4* h4 = (float4*)(h + (size_t)n * 32);
#pragma unroll
  for (int j = 0; j < 8; j++) h4[j] = make_float4(hh[4*j], hh[4*j+1], hh[4*j+2], hh[4*j+3]);
  Vp[n] = make_float2(1.0f, 0.0f);
  float av[32], bv[32];
#pragma unroll
  for (int j = 0; j < 32; j++) { av[j] = Wm[j]; bv[j] = Wm[34 * 32 + j] + bm[j]; }
#pragma unroll 1
  for (int k = 0; k < 32; k++) {
    float hk = hh[k];
#pragma unroll
    for (int j = 0; j < 32; j++) {
      av[j] = fmaf(hk, Wm[(2 + k) * 32 + j], av[j]);
      bv[j] = fmaf(hk, Wm[(36 + k) * 32 + j], bv[j]);
    }
  }
  u32x4* dst = (u32x4*)(a + (size_t)n * 32);
#pragma unroll
  for (int g = 0; g < 4; g++) {
    u32x4 p;
    p.x = f2h2(av[g*8+0], av[g*8+1]);
    p.y = f2h2(av[g*8+2], av[g*8+3]);
    p.z = f2h2(av[g*8+4], av[g*8+5]);
    p.w = f2h2(av[g*8+6], av[g*8+7]);
    dst[g] = p;
  }
  float4* b4 = (float4*)(bp + (size_t)n * 32);
#pragma unroll
  for (int j = 0; j < 8; j++) b4[j] = make_float4(bv[4*j], bv[4*j+1], bv[4*j+2], bv[4*j+3]);
}

// ---------------- per-layer edge aggregation: CSR quad-gather, register accum, NO atomics ----------------
// 4 lanes per node (8 ch each); node's edges sender-granule-sorted; record load is quad-broadcast.

__global__ __launch_bounds__(256) void k_edge(const __half* __restrict__ a, const float* __restrict__ bp,
                                              const int* __restrict__ row_off, const f32x4* __restrict__ sorted,
                                              const float* __restrict__ Wm, float* __restrict__ agg) {
  int t = threadIdx.x;
  int n = blockIdx.x * 64 + (t >> 2);
  if (n >= NN) return;
  int ch = (t & 3) * 8;
  const float* wr = Wm + 68 * 32 + ch;
  float w0[8], w1[8];
#pragma unroll
  for (int j = 0; j < 8; j++) { w0[j] = wr[j]; w1[j] = wr[32 + j]; }
  const float4 bna = *(const float4*)(bp + (size_t)n * 32 + ch);
  const float4 bnb = *(const float4*)(bp + (size_t)n * 32 + ch + 4);
  float bn[8] = {bna.x, bna.y, bna.z, bna.w, bnb.x, bnb.y, bnb.z, bnb.w};
  float acc[8] = {0.f, 0.f, 0.f, 0.f, 0.f, 0.f, 0.f, 0.f};
  int e0 = row_off[n], e1 = row_off[n + 1];
  f32x4 rec = {0.f, 0.f, 0.f, 0.f};
  if (e0 < e1) rec = __builtin_nontemporal_load(sorted + e0);
#pragma unroll 2
  for (int e = e0; e < e1; ++e) {
    int pk = __float_as_int(rec.x);
    float c0 = rec.y, c1 = rec.z, mk = rec.w;
    const u32x4 pa = *(const u32x4*)(a + (size_t)(pk >> 6) * 32 + ch);  // 16B of sender's 64B line
    if (e + 1 < e1) rec = __builtin_nontemporal_load(sorted + e + 1);   // prefetch next record
    float2 f0 = h2f2(pa.x), f1 = h2f2(pa.y), f2 = h2f2(pa.z), f3 = h2f2(pa.w);
    float av[8] = {f0.x, f0.y, f1.x, f1.y, f2.x, f2.y, f3.x, f3.y};
#pragma unroll
    for (int j = 0; j < 8; j++)
      acc[j] = fmaf(fmaxf(av[j] + fmaf(c0, w0[j], fmaf(c1, w1[j], bn[j])), 0.f), mk, acc[j]);
  }
  float* gp = agg + (size_t)n * 32 + ch;
  *(float4*)gp       = make_float4(acc[0], acc[1], acc[2], acc[3]);
  *(float4*)(gp + 4) = make_float4(acc[4], acc[5], acc[6], acc[7]);
}

// ---------------- per-layer node update (+ next-layer projections fused) ----------------

__global__ __launch_bounds__(256) void k_node(const float* __restrict__ agg,
                                              const float* __restrict__ Wu, const float* __restrict__ bu,
                                              const float* __restrict__ Wd, const float* __restrict__ bd,
                                              const float* __restrict__ Wm, const float* __restrict__ bm,
                                              float* __restrict__ h, __half* __restrict__ a,
                                              float* __restrict__ bp, float2* __restrict__ Vp,
                                              float2* __restrict__ out, int last) {
  int n = blockIdx.x * 256 + threadIdx.x;
  if (n >= NN) return;
  float2 vp = Vp[n];
  float v0 = vp.x, v1 = vp.y;
  float hh[32], ag[32];
  const float4* h4 = (const float4*)(h + (size_t)n * 32);
  const float4* g4 = (const float4*)(agg + (size_t)n * 32);
#pragma unroll
  for (int jj = 0; jj < 8; jj++) {
    float4 x = h4[jj];
    hh[4*jj] = x.x; hh[4*jj+1] = x.y; hh[4*jj+2] = x.z; hh[4*jj+3] = x.w;
    float4 y = g4[jj];
    ag[4*jj] = y.x; ag[4*jj+1] = y.y; ag[4*jj+2] = y.z; ag[4*jj+3] = y.w;
  }
  float vo[32];
#pragma unroll
  for (int j = 0; j < 32; j++) vo[j] = fmaf(v0, Wu[j], fmaf(v1, Wu[32 + j], bu[j]));
#pragma unroll 1
  for (int k = 0; k < 32; k++) {
    float hk = hh[k], ak = ag[k];
#pragma unroll
    for (int j = 0; j < 32; j++) {
      vo[j] = fmaf(hk, Wu[(2 + k) * 32 + j], vo[j]);
      vo[j] = fmaf(ak, Wu[(34 + k) * 32 + j], vo[j]);
    }
  }
#pragma unroll
  for (int j = 0; j < 32; j++) hh[j] = fmaxf(vo[j], 0.0f);
  float d0 = bd[0], d1 = bd[1];
#pragma unroll 1
  for (int k = 0; k < 32; k++) {
    d0 = fmaf(hh[k], Wd[2 * k], d0);
    d1 = fmaf(hh[k], Wd[2 * k + 1], d1);
  }
  v0 += d0;
  v1 += d1;
  if (last) {
    out[n] = make_float2(v0, v1);
    return;
  }
  Vp[n] = make_float2(v0, v1);
  float4* hw4 = (float4*)(h + (size_t)n * 32);
#pragma unroll
  for (int jj = 0; jj < 8; jj++) hw4[jj] = make_float4(hh[4*jj], hh[4*jj+1], hh[4*jj+2], hh[4*jj+3]);
  float av[32], bv[32];
#pragma unroll
  for (int j = 0; j < 32; j++) {
    av[j] = fmaf(v0, Wm[j], v1 * Wm[32 + j]);
    bv[j] = fmaf(v0, Wm[34 * 32 + j], fmaf(v1, Wm[35 * 32 + j], bm[j]));
  }
#pragma unroll 1
  for (int k = 0; k < 32; k++) {
    float hk = hh[k];
#pragma unroll
    for (int j = 0; j < 32; j++) {
      av[j] = fmaf(hk, Wm[(2 + k) * 32 + j], av[j]);
      bv[j] = fmaf(hk, Wm[(36 + k) * 32 + j], bv[j]);
    }
  }
  u32x4* dst = (u32x4*)(a + (size_t)n * 32);
#pragma unroll
  for (int g = 0; g < 4; g++) {
    u32x4 p;
    p.x = f2h2(av[g*8+0], av[g*8+1]);
    p.y = f2h2(av[g*8+2], av[g*8+3]);
    p.z = f2h2(av[g*8+4], av[g*8+5]);
    p.w = f2h2(av[g*8+6], av[g*8+7]);
    dst[g] = p;
  }
  float4* b4 = (float4*)(bp + (size_t)n * 32);
#pragma unroll
  for (int jj = 0; jj < 8; jj++) b4[jj] = make_float4(bv[4*jj], bv[4*jj+1], bv[4*jj+2], bv[4*jj+3]);
}

// ---------------- launch ----------------

extern "C" void kernel_launch(void* const* d_in, const int* in_sizes, int n_in,
                              void* d_out, int out_size, void* d_ws, size_t ws_size,
                              hipStream_t stream) {
  const float* PQ   = (const float*)d_in[0];
  const int*   send = (const int*)d_in[1];
  const int*   recv = (const int*)d_in[2];
  const float* ef   = (const float*)d_in[3];
  const float* mask = (const float*)d_in[4];
  const float* Win  = (const float*)d_in[5];
  const float* bin  = (const float*)d_in[6];
  const float* Wmsg = (const float*)d_in[7];   // [3,70,32]
  const float* bmsg = (const float*)d_in[8];   // [3,32]
  const float* Wupd = (const float*)d_in[9];   // [3,66,32]
  const float* bupd = (const float*)d_in[10];  // [3,32]
  const float* Wdel = (const float*)d_in[11];  // [3,32,2]
  const float* bdel = (const float*)d_in[12];  // [3,2]
  float2* out = (float2*)d_out;

  char* w = (char*)d_ws;
  auto alloc = [&](size_t bytes) {
    char* p = w;
    w += (bytes + 255) & ~(size_t)255;
    return p;
  };
  float4* sorted = (float4*)alloc((size_t)NE * 16);
  int* histmat = (int*)alloc((size_t)NB * NCH * 4);  // then in-place -> boffc
  int* total   = (int*)alloc((size_t)NB * 4);
  int* boff    = (int*)alloc(((size_t)NB + 1) * 4);
  int* row_off = (int*)alloc(((size_t)NN + 1) * 4);
  float* h    = (float*)alloc((size_t)NN * 32 * 4);
  __half* a   = (__half*)alloc((size_t)NN * 32 * 2);
  float* bp   = (float*)alloc((size_t)NN * 32 * 4);
  float* agg  = (float*)alloc((size_t)NN * 32 * 4);
  float2* Vp  = (float2*)alloc((size_t)NN * 8);

  k_hist<<<NCH, 256, 0, stream>>>(recv, histmat);
  k_scanA<<<NB, 64, 0, stream>>>(histmat, total);
  k_scanB<<<1, 256, 0, stream>>>(total, boff);
  k_scanC<<<NB, 64, 0, stream>>>(histmat, boff);
  k_scat<<<NCH, 256, 0, stream>>>(send, recv, (const float2*)ef, mask, histmat, sorted);
  k_bsort<<<NB, 256, 0, stream>>>(boff, sorted, row_off);

  k_init<<<NBLK, 256, 0, stream>>>((const float2*)PQ, Win, bin, Wmsg, bmsg, h, a, bp, Vp);

  for (int l = 0; l < 3; l++) {
    int last = (l == 2) ? 1 : 0;
    int lnext = (l + 1) % 3;
    k_edge<<<NB, 256, 0, stream>>>(a, bp, row_off, (const f32x4*)sorted, Wmsg + l * 70 * 32, agg);
    k_node<<<NBLK, 256, 0, stream>>>(agg, Wupd + l * 66 * 32, bupd + l * 32,
                                     Wdel + l * 64, bdel + l * 2,
                                     Wmsg + lnext * 70 * 32, bmsg + lnext * 32,
                                     h, a, bp, Vp, out, last);
  }
}